// Round 1
// baseline (856.315 us; speedup 1.0000x reference)
//
#include <hip/hip_runtime.h>

typedef __bf16 bf16x8 __attribute__((ext_vector_type(8)));
typedef float f32x4 __attribute__((ext_vector_type(4)));

#define LDK 40   // padded LDS k-stride (bf16 elems): 80 B rows, 16B-aligned
#define NB 16
#define C_ 512
#define CI 256
#define HW 4096
#define KSPLIT 4
#define KCHUNK (HW / KSPLIT)

__device__ __forceinline__ float bf2f(unsigned short u){
  union { unsigned int u; float f; } c; c.u = ((unsigned int)u) << 16; return c.f;
}
__device__ __forceinline__ unsigned short f2bf(float f){
  union { float f; unsigned int u; } c; c.f = f;
  unsigned int u = c.u + 0x7fffu + ((c.u >> 16) & 1u);
  return (unsigned short)(u >> 16);
}
__device__ __forceinline__ float read_val(const void* p, int i, bool f32){
  return f32 ? ((const float*)p)[i] : bf2f(((const unsigned short*)p)[i]);
}

// ---- staging helpers (256 threads) ----

// 128 rows x 32 k bf16 row-major -> LDS [row][k]
__device__ __forceinline__ void stage_rm(const unsigned short* __restrict__ src, int stride,
                                         unsigned short* dst, int t){
  #pragma unroll
  for (int it = 0; it < 2; ++it){
    int idx = t + it*256;
    int row = idx >> 2;
    int ko  = (idx & 3) * 8;
    *(uint4*)(dst + row*LDK + ko) = *(const uint4*)(src + (size_t)row*stride + ko);
  }
}

// 32 src-rows x 128 src-cols bf16 -> LDS transposed dst[col][row]
__device__ __forceinline__ void stage_tr(const unsigned short* __restrict__ src, int stride,
                                         unsigned short* dst, int t){
  #pragma unroll
  for (int it = 0; it < 2; ++it){
    int idx = t + it*256;
    int row = idx >> 4;              // 0..31
    int co  = (idx & 15) * 8;
    uint4 vv = *(const uint4*)(src + (size_t)row*stride + co);
    unsigned short e[8]; *(uint4*)e = vv;
    #pragma unroll
    for (int k = 0; k < 8; ++k) dst[(co + k)*LDK + row] = e[k];
  }
}

// one 32-wide k-step: wave (wm,wn) covers 64x64, 16 mfma
__device__ __forceinline__ void mfma_step(const unsigned short* As, const unsigned short* Bs,
                                          f32x4 acc[4][4], int wm, int wn, int lane){
  const int r = lane & 15, q = lane >> 4;
  bf16x8 a[4], b[4];
  #pragma unroll
  for (int i = 0; i < 4; ++i)
    a[i] = *(const bf16x8*)(As + (wm*64 + 16*i + r)*LDK + 8*q);
  #pragma unroll
  for (int j = 0; j < 4; ++j)
    b[j] = *(const bf16x8*)(Bs + (wn*64 + 16*j + r)*LDK + 8*q);
  #pragma unroll
  for (int i = 0; i < 4; ++i)
    #pragma unroll
    for (int j = 0; j < 4; ++j)
      acc[i][j] = __builtin_amdgcn_mfma_f32_16x16x32_bf16(a[i], b[j], acc[i][j], 0, 0, 0);
}

// ---- K0: dtype detect. fp32 inputs read as bf16 halves contain exp==0xFF patterns.
__global__ __launch_bounds__(256) void k_detect(const unsigned short* __restrict__ x, int* flag){
  const int t = threadIdx.x;
  int cnt = 0;
  for (int i = t; i < 65536; i += 256){
    unsigned short u = x[i];
    if (((u >> 7) & 0xFF) == 0xFF) cnt++;
  }
  __shared__ int red[256];
  red[t] = cnt; __syncthreads();
  for (int s2 = 128; s2 > 0; s2 >>= 1){
    if (t < s2) red[t] += red[t + s2];
    __syncthreads();
  }
  if (t == 0) flag[0] = (red[0] > 0) ? 1 : 0;
}

// ---- K0b: convert weights to canonical buffers (theta/phi split hi/lo; g/W hi; biases fp32)
__global__ __launch_bounds__(256) void k_wconv(const void* tw, const void* pw, const void* gw,
    const void* Ww, const void* gb, const void* tb, const void* pb, const void* Wb,
    const void* gam, const void* bet, const int* __restrict__ flag,
    unsigned short* twh, unsigned short* twl, unsigned short* phh, unsigned short* phl,
    unsigned short* gwc, unsigned short* Wwc, float* biasf){
  const bool f32 = (*flag != 0);
  const int bid = blockIdx.x, t = threadIdx.x;
  if (bid < 2048){
    const int seg = bid >> 9;
    const int i = (bid & 511)*256 + t;
    if (seg == 0){
      float w = read_val(tw, i, f32);
      unsigned short h = f2bf(w);
      twh[i] = h; twl[i] = f2bf(w - bf2f(h));
    } else if (seg == 1){
      float w = read_val(pw, i, f32);
      unsigned short h = f2bf(w);
      phh[i] = h; phl[i] = f2bf(w - bf2f(h));
    } else if (seg == 2){
      gwc[i] = f2bf(read_val(gw, i, f32));
    } else {
      Wwc[i] = f2bf(read_val(Ww, i, f32));
    }
  } else {
    const int i = (bid - 2048)*256 + t;
    if (i < 2304){
      float v;
      if      (i <  256) v = read_val(gb,  i,        f32);
      else if (i <  512) v = read_val(tb,  i - 256,  f32);
      else if (i <  768) v = read_val(pb,  i - 512,  f32);
      else if (i < 1280) v = read_val(Wb,  i - 768,  f32);
      else if (i < 1792) v = read_val(gam, i - 1280, f32);
      else               v = read_val(bet, i - 1792, f32);
      biasf[i] = v;
    }
  }
}

// ---- K0c: x fp32 -> xh/xl bf16 (exact hi/lo split) + rowsums s. For bf16 input: s only.
__global__ __launch_bounds__(256) void k_xconv(const void* __restrict__ xraw,
    const int* __restrict__ flag, unsigned short* __restrict__ xh,
    unsigned short* __restrict__ xl, float* __restrict__ s){
  const bool f32 = (*flag != 0);
  const int bc = blockIdx.x, t = threadIdx.x;   // bc = b*C_ + c
  float sum = 0.f;
  if (f32){
    const float* xr = (const float*)xraw + (size_t)bc*HW;
    unsigned short* oh = xh + (size_t)bc*HW;
    unsigned short* ol = xl + (size_t)bc*HW;
    #pragma unroll
    for (int it = 0; it < 4; ++it){
      const int off = it*1024 + t*4;
      f32x4 v = *(const f32x4*)(xr + off);
      unsigned int wh[2], wl[2];
      #pragma unroll
      for (int k = 0; k < 2; ++k){
        unsigned short h0 = f2bf(v[2*k]),   h1 = f2bf(v[2*k+1]);
        unsigned short l0 = f2bf(v[2*k]   - bf2f(h0));
        unsigned short l1 = f2bf(v[2*k+1] - bf2f(h1));
        wh[k] = (unsigned int)h0 | ((unsigned int)h1 << 16);
        wl[k] = (unsigned int)l0 | ((unsigned int)l1 << 16);
      }
      sum += v[0] + v[1] + v[2] + v[3];
      *(uint2*)(oh + off) = make_uint2(wh[0], wh[1]);
      *(uint2*)(ol + off) = make_uint2(wl[0], wl[1]);
    }
  } else {
    const unsigned short* xr = (const unsigned short*)xraw + (size_t)bc*HW;
    #pragma unroll
    for (int it = 0; it < 2; ++it){
      const int off = it*2048 + t*8;
      uint4 raw = *(const uint4*)(xr + off);
      unsigned int wd[4] = {raw.x, raw.y, raw.z, raw.w};
      #pragma unroll
      for (int k = 0; k < 4; ++k)
        sum += bf2f((unsigned short)(wd[k] & 0xffff)) + bf2f((unsigned short)(wd[k] >> 16));
    }
  }
  #pragma unroll
  for (int off = 1; off < 64; off <<= 1) sum += __shfl_xor(sum, off);
  __shared__ float r1[4];
  if ((t & 63) == 0) r1[t >> 6] = sum;
  __syncthreads();
  if (t == 0) s[bc] = r1[0] + r1[1] + r1[2] + r1[3];
}

// ---- K1a: partial Gram. Upper tiles (bm<=bn) only, k-split x4.
// Gp layout: [b][tile(10)][ks(4)][128][128] fp32
__global__ __launch_bounds__(256) void k_gram(const void* __restrict__ xraw,
    const unsigned short* __restrict__ xh, const unsigned short* __restrict__ xl,
    const int* __restrict__ flag, float* __restrict__ Gp){
  const bool f32 = (*flag != 0);
  const int b = blockIdx.z, ks = blockIdx.y, tile = blockIdx.x;
  int bm, bn;
  if      (tile < 4){ bm = 0; bn = tile; }
  else if (tile < 7){ bm = 1; bn = tile - 3; }
  else if (tile < 9){ bm = 2; bn = tile - 5; }
  else              { bm = 3; bn = 3; }
  const int t = threadIdx.x, lane = t & 63, w = t >> 6, wm = w >> 1, wn = w & 1;
  __shared__ unsigned short Ah[128*LDK];
  __shared__ unsigned short Al[128*LDK];
  __shared__ unsigned short Bh[128*LDK];
  __shared__ unsigned short Bl[128*LDK];
  f32x4 acc[4][4] = {};
  const bool diag = (bm == bn);
  const unsigned short* xhb = f32 ? (xh + (size_t)b*C_*HW)
                                  : ((const unsigned short*)xraw + (size_t)b*C_*HW);
  const unsigned short* xlb = xl + (size_t)b*C_*HW;
  const int kbeg = ks*KCHUNK, kend = kbeg + KCHUNK;
  for (int k0 = kbeg; k0 < kend; k0 += 32){
    stage_rm(xhb + (size_t)(bm*128)*HW + k0, HW, Ah, t);
    if (f32) stage_rm(xlb + (size_t)(bm*128)*HW + k0, HW, Al, t);
    if (!diag){
      stage_rm(xhb + (size_t)(bn*128)*HW + k0, HW, Bh, t);
      if (f32) stage_rm(xlb + (size_t)(bn*128)*HW + k0, HW, Bl, t);
    }
    __syncthreads();
    const unsigned short* BhU = diag ? Ah : Bh;
    const unsigned short* BlU = diag ? Al : Bl;
    mfma_step(Ah, BhU, acc, wm, wn, lane);
    if (f32){
      mfma_step(Ah, BlU, acc, wm, wn, lane);   // xh.xl^T
      mfma_step(Al, BhU, acc, wm, wn, lane);   // xl.xh^T
    }
    __syncthreads();
  }
  float* Gt = Gp + (((size_t)b*10 + tile)*KSPLIT + ks)*16384;
  const int r = lane & 15, q = lane >> 4;
  #pragma unroll
  for (int i = 0; i < 4; ++i)
    #pragma unroll
    for (int j = 0; j < 4; ++j)
      #pragma unroll
      for (int ii = 0; ii < 4; ++ii){
        int row = wm*64 + 16*i + 4*q + ii;
        int col = wn*64 + 16*j + r;
        Gt[row*128 + col] = acc[i][j][ii];
      }
}

// ---- K1c: reduce k-split partials, mirror across diagonal, emit Gh/Gl bf16
__global__ __launch_bounds__(256) void k_gred(const float* __restrict__ Gp,
    unsigned short* __restrict__ Gh, unsigned short* __restrict__ Gl){
  const int b = blockIdx.z, bmO = blockIdx.y, bnO = blockIdx.x, t = threadIdx.x;
  const int lo = bmO < bnO ? bmO : bnO;
  const int hi = bmO < bnO ? bnO : bmO;
  const int tile = (lo == 0) ? hi : (lo == 1) ? 3 + hi : (lo == 2) ? 5 + hi : 9;
  const float* src = Gp + ((size_t)b*10 + tile)*KSPLIT*16384;
  unsigned short* ghB = Gh + (size_t)b*C_*C_;
  unsigned short* glB = Gl + (size_t)b*C_*C_;
  if (bmO <= bnO){
    #pragma unroll
    for (int i = 0; i < 16; ++i){
      const int off = i*1024 + t*4;
      f32x4 v = *(const f32x4*)(src + off);
      #pragma unroll
      for (int ks = 1; ks < KSPLIT; ++ks){
        f32x4 u2 = *(const f32x4*)(src + ks*16384 + off);
        v[0] += u2[0]; v[1] += u2[1]; v[2] += u2[2]; v[3] += u2[3];
      }
      const int row = off >> 7, col = off & 127;
      unsigned int wh[2], wl[2];
      #pragma unroll
      for (int k = 0; k < 2; ++k){
        unsigned short h0 = f2bf(v[2*k]),   h1 = f2bf(v[2*k+1]);
        unsigned short l0 = f2bf(v[2*k]   - bf2f(h0));
        unsigned short l1 = f2bf(v[2*k+1] - bf2f(h1));
        wh[k] = (unsigned int)h0 | ((unsigned int)h1 << 16);
        wl[k] = (unsigned int)l0 | ((unsigned int)l1 << 16);
      }
      size_t o = (size_t)(bmO*128 + row)*C_ + bnO*128 + col;
      *(uint2*)(ghB + o) = make_uint2(wh[0], wh[1]);
      *(uint2*)(glB + o) = make_uint2(wl[0], wl[1]);
    }
  } else {
    // transposed copy of upper tile via LDS, 32-col chunks
    __shared__ float ldz[32*129];
    const int rr = t >> 1, cseg = (t & 1)*16;
    const int orl = t >> 3, oseg = (t & 7)*16;
    for (int cc = 0; cc < 4; ++cc){
      float vals[16];
      #pragma unroll
      for (int j = 0; j < 4; ++j){
        const int so = rr*128 + cc*32 + cseg + j*4;
        f32x4 v = *(const f32x4*)(src + so);
        #pragma unroll
        for (int ks = 1; ks < KSPLIT; ++ks){
          f32x4 u2 = *(const f32x4*)(src + ks*16384 + so);
          v[0] += u2[0]; v[1] += u2[1]; v[2] += u2[2]; v[3] += u2[3];
        }
        vals[4*j] = v[0]; vals[4*j+1] = v[1]; vals[4*j+2] = v[2]; vals[4*j+3] = v[3];
      }
      __syncthreads();
      #pragma unroll
      for (int e = 0; e < 16; ++e) ldz[(cseg + e)*129 + rr] = vals[e];
      __syncthreads();
      unsigned int wh[8], wl[8];
      #pragma unroll
      for (int k = 0; k < 8; ++k){
        float f0 = ldz[orl*129 + oseg + 2*k];
        float f1 = ldz[orl*129 + oseg + 2*k + 1];
        unsigned short h0 = f2bf(f0), h1 = f2bf(f1);
        unsigned short l0 = f2bf(f0 - bf2f(h0)), l1 = f2bf(f1 - bf2f(h1));
        wh[k] = (unsigned int)h0 | ((unsigned int)h1 << 16);
        wl[k] = (unsigned int)l0 | ((unsigned int)l1 << 16);
      }
      size_t o = (size_t)(bmO*128 + cc*32 + orl)*C_ + bnO*128 + oseg;
      *(uint4*)(ghB + o)     = make_uint4(wh[0], wh[1], wh[2], wh[3]);
      *(uint4*)(ghB + o + 8) = make_uint4(wh[4], wh[5], wh[6], wh[7]);
      *(uint4*)(glB + o)     = make_uint4(wl[0], wl[1], wl[2], wl[3]);
      *(uint4*)(glB + o + 8) = make_uint4(wl[4], wl[5], wl[6], wl[7]);
    }
  }
}

// ---- K1b: gT[b] (4096x256) = x^T gw^T + g_b   (reads xh when fp32)
__global__ __launch_bounds__(256) void k_gconv(const void* __restrict__ xraw,
    const int* __restrict__ flag, const unsigned short* __restrict__ xh,
    const unsigned short* __restrict__ gwc,
    const float* __restrict__ gbf, unsigned short* __restrict__ gT){
  const bool f32 = (*flag != 0);
  const int b = blockIdx.z, mt = blockIdx.x, nt = blockIdx.y;
  const int t = threadIdx.x, lane = t & 63, w = t >> 6, wm = w >> 1, wn = w & 1;
  __shared__ unsigned short As[128*LDK];
  __shared__ unsigned short Bs[128*LDK];
  f32x4 acc[4][4] = {};
  const unsigned short* xb = f32 ? (xh + (size_t)b*C_*HW)
                                 : ((const unsigned short*)xraw + (size_t)b*C_*HW);
  for (int k0 = 0; k0 < C_; k0 += 32){
    stage_tr(xb + (size_t)k0*HW + mt*128, HW, As, t);
    stage_rm(gwc + (size_t)nt*128*C_ + k0, C_, Bs, t);
    __syncthreads();
    mfma_step(As, Bs, acc, wm, wn, lane);
    __syncthreads();
  }
  unsigned short* gTb = gT + (size_t)b*HW*CI;
  const int r = lane & 15, q = lane >> 4;
  #pragma unroll
  for (int j = 0; j < 4; ++j){
    int col = nt*128 + wn*64 + 16*j + r;
    float bias = gbf[col];
    #pragma unroll
    for (int i = 0; i < 4; ++i)
      #pragma unroll
      for (int ii = 0; ii < 4; ++ii){
        int row = mt*128 + wm*64 + 16*i + 4*q + ii;
        gTb[(size_t)row*CI + col] = f2bf(acc[i][j][ii] + bias);
      }
  }
}

// ---- K2: T[b] = theta_w @ G[b]   (theta split, G pre-split into Gh/Gl)
__global__ __launch_bounds__(256) void k_T(const unsigned short* __restrict__ twh,
    const unsigned short* __restrict__ twl, const int* __restrict__ flag,
    const unsigned short* __restrict__ Gh, const unsigned short* __restrict__ Gl,
    unsigned short* __restrict__ Th, unsigned short* __restrict__ Tl){
  const bool f32 = (*flag != 0);
  const int b = blockIdx.z, nt = blockIdx.x, mt = blockIdx.y;
  const int t = threadIdx.x, lane = t & 63, w = t >> 6, wm = w >> 1, wn = w & 1;
  __shared__ unsigned short Ath[128*LDK];
  __shared__ unsigned short Atl[128*LDK];
  __shared__ unsigned short Bh[128*LDK];
  __shared__ unsigned short Bl[128*LDK];
  const unsigned short* Ghb = Gh + (size_t)b*C_*C_;
  const unsigned short* Glb = Gl + (size_t)b*C_*C_;
  f32x4 acc[4][4] = {};
  for (int k0 = 0; k0 < C_; k0 += 32){
    stage_rm(twh + (size_t)mt*128*C_ + k0, C_, Ath, t);
    if (f32) stage_rm(twl + (size_t)mt*128*C_ + k0, C_, Atl, t);
    stage_rm(Ghb + (size_t)nt*128*C_ + k0, C_, Bh, t);
    stage_rm(Glb + (size_t)nt*128*C_ + k0, C_, Bl, t);
    __syncthreads();
    mfma_step(Ath, Bh, acc, wm, wn, lane);
    mfma_step(Ath, Bl, acc, wm, wn, lane);
    if (f32) mfma_step(Atl, Bh, acc, wm, wn, lane);
    __syncthreads();
  }
  unsigned short* Thb = Th + (size_t)b*CI*C_;
  unsigned short* Tlb = Tl + (size_t)b*CI*C_;
  const int r = lane & 15, q = lane >> 4;
  #pragma unroll
  for (int i = 0; i < 4; ++i)
    #pragma unroll
    for (int j = 0; j < 4; ++j)
      #pragma unroll
      for (int ii = 0; ii < 4; ++ii){
        int row = mt*128 + wm*64 + 16*i + 4*q + ii;
        int col = nt*128 + wn*64 + 16*j + r;
        float vv = acc[i][j][ii];
        unsigned short h = f2bf(vv);
        Thb[(size_t)row*C_ + col] = h;
        Tlb[(size_t)row*C_ + col] = f2bf(vv - bf2f(h));
      }
}

// ---- K3: f[b] = (Th+Tl) @ phi^T  with phi split
__global__ __launch_bounds__(256) void k_f(const unsigned short* __restrict__ Th,
    const unsigned short* __restrict__ Tl, const unsigned short* __restrict__ phh,
    const unsigned short* __restrict__ phl, const int* __restrict__ flag,
    float* __restrict__ f){
  const bool f32 = (*flag != 0);
  const int b = blockIdx.z, nt = blockIdx.x, mt = blockIdx.y;
  const int t = threadIdx.x, lane = t & 63, w = t >> 6, wm = w >> 1, wn = w & 1;
  __shared__ unsigned short ATh[128*LDK];
  __shared__ unsigned short ATl[128*LDK];
  __shared__ unsigned short Bph[128*LDK];
  __shared__ unsigned short Bpl[128*LDK];
  f32x4 acc[4][4] = {};
  const unsigned short* Thb = Th + (size_t)b*CI*C_;
  const unsigned short* Tlb = Tl + (size_t)b*CI*C_;
  for (int k0 = 0; k0 < C_; k0 += 32){
    stage_rm(Thb + (size_t)mt*128*C_ + k0, C_, ATh, t);
    stage_rm(Tlb + (size_t)mt*128*C_ + k0, C_, ATl, t);
    stage_rm(phh + (size_t)nt*128*C_ + k0, C_, Bph, t);
    if (f32) stage_rm(phl + (size_t)nt*128*C_ + k0, C_, Bpl, t);
    __syncthreads();
    mfma_step(ATh, Bph, acc, wm, wn, lane);
    mfma_step(ATl, Bph, acc, wm, wn, lane);
    if (f32) mfma_step(ATh, Bpl, acc, wm, wn, lane);
    __syncthreads();
  }
  float* fb = f + (size_t)b*CI*CI;
  const int r = lane & 15, q = lane >> 4;
  #pragma unroll
  for (int i = 0; i < 4; ++i)
    #pragma unroll
    for (int j = 0; j < 4; ++j)
      #pragma unroll
      for (int ii = 0; ii < 4; ++ii){
        int row = mt*128 + wm*64 + 16*i + 4*q + ii;
        int col = nt*128 + wn*64 + 16*j + r;
        fb[(size_t)row*CI + col] = acc[i][j][ii];
      }
}

// u = theta_w @ s, v = phi_w @ s
__global__ __launch_bounds__(256) void k_uv(const unsigned short* __restrict__ twh,
    const unsigned short* __restrict__ twl, const unsigned short* __restrict__ phh,
    const unsigned short* __restrict__ phl, const float* __restrict__ s,
    float* __restrict__ u, float* __restrict__ v){
  const int b = blockIdx.x, c = threadIdx.x;
  __shared__ float sl[C_];
  sl[c] = s[(size_t)b*C_ + c];
  sl[c + 256] = s[(size_t)b*C_ + c + 256];
  __syncthreads();
  float su = 0.f, sv = 0.f;
  for (int e = 0; e < C_; ++e){
    su += (bf2f(twh[(size_t)c*C_ + e]) + bf2f(twl[(size_t)c*C_ + e])) * sl[e];
    sv += (bf2f(phh[(size_t)c*C_ + e]) + bf2f(phl[(size_t)c*C_ + e])) * sl[e];
  }
  u[(size_t)b*CI + c] = su;
  v[(size_t)b*CI + c] = sv;
}

// ---- K4: softmax rows of f (+ rank-1 bias corrections), write S bf16
__global__ __launch_bounds__(256) void k_softmax(const float* __restrict__ f,
    const float* __restrict__ u, const float* __restrict__ v,
    const float* __restrict__ tbf, const float* __restrict__ pbf,
    unsigned short* __restrict__ S){
  const int b = blockIdx.y;
  const int c = blockIdx.x*4 + (threadIdx.x >> 6);
  const int lane = threadIdx.x & 63;
  const float* fr = f + ((size_t)b*CI + c)*CI;
  f32x4 val = *(const f32x4*)(fr + lane*4);
  const float uc = u[(size_t)b*CI + c];
  const float tbc = tbf[c];
  float vv[4];
  #pragma unroll
  for (int k = 0; k < 4; ++k){
    int d = lane*4 + k;
    float pbd = pbf[d];
    vv[k] = val[k] + uc*pbd + tbc*(v[(size_t)b*CI + d] + 4096.0f*pbd);
  }
  float mx = fmaxf(fmaxf(vv[0], vv[1]), fmaxf(vv[2], vv[3]));
  #pragma unroll
  for (int off = 1; off < 64; off <<= 1) mx = fmaxf(mx, __shfl_xor(mx, off));
  float e[4], sum = 0.f;
  #pragma unroll
  for (int k = 0; k < 4; ++k){ e[k] = expf(vv[k] - mx); sum += e[k]; }
  #pragma unroll
  for (int off = 1; off < 64; off <<= 1) sum += __shfl_xor(sum, off);
  float inv = 1.0f / sum;
  uint2 pack;
  pack.x = (unsigned int)f2bf(e[0]*inv) | ((unsigned int)f2bf(e[1]*inv) << 16);
  pack.y = (unsigned int)f2bf(e[2]*inv) | ((unsigned int)f2bf(e[3]*inv) << 16);
  *(uint2*)(S + ((size_t)b*CI + c)*CI + lane*4) = pack;
}

// ---- K5: M2[b] = W_w @ S[b]
__global__ __launch_bounds__(256) void k_M2(const unsigned short* __restrict__ Wwc,
                                            const unsigned short* __restrict__ S,
                                            unsigned short* __restrict__ M2){
  const int b = blockIdx.z, nt = blockIdx.x, mt = blockIdx.y;
  const int t = threadIdx.x, lane = t & 63, w = t >> 6, wm = w >> 1, wn = w & 1;
  __shared__ unsigned short As[128*LDK];
  __shared__ unsigned short Bs[128*LDK];
  f32x4 acc[4][4] = {};
  for (int k0 = 0; k0 < CI; k0 += 32){
    stage_rm(Wwc + (size_t)mt*128*CI + k0, CI, As, t);
    stage_tr(S + (size_t)b*CI*CI + (size_t)k0*CI + nt*128, CI, Bs, t);
    __syncthreads();
    mfma_step(As, Bs, acc, wm, wn, lane);
    __syncthreads();
  }
  unsigned short* M2b = M2 + (size_t)b*C_*CI;
  const int r = lane & 15, q = lane >> 4;
  #pragma unroll
  for (int i = 0; i < 4; ++i)
    #pragma unroll
    for (int j = 0; j < 4; ++j)
      #pragma unroll
      for (int ii = 0; ii < 4; ++ii){
        int row = mt*128 + wm*64 + 16*i + 4*q + ii;
        int col = nt*128 + wn*64 + 16*j + r;
        M2b[(size_t)row*CI + col] = f2bf(acc[i][j][ii]);
      }
}

// ---- K6: z[b] = M2[b] @ g[b] + W_b
__global__ __launch_bounds__(256) void k_z(const unsigned short* __restrict__ M2,
                                           const unsigned short* __restrict__ gT,
                                           const float* __restrict__ Wbf,
                                           unsigned short* __restrict__ z){
  const int b = blockIdx.z, nt = blockIdx.x, mt = blockIdx.y;
  const int t = threadIdx.x, lane = t & 63, w = t >> 6, wm = w >> 1, wn = w & 1;
  __shared__ unsigned short As[128*LDK];
  __shared__ unsigned short Bs[128*LDK];
  const unsigned short* M2b = M2 + (size_t)b*C_*CI;
  const unsigned short* gTb = gT + (size_t)b*HW*CI;
  f32x4 acc[4][4] = {};
  for (int k0 = 0; k0 < CI; k0 += 32){
    stage_rm(M2b + (size_t)mt*128*CI + k0, CI, As, t);
    stage_rm(gTb + (size_t)nt*128*CI + k0, CI, Bs, t);
    __syncthreads();
    mfma_step(As, Bs, acc, wm, wn, lane);
    __syncthreads();
  }
  unsigned short* zb = z + (size_t)b*C_*HW;
  const int r = lane & 15, q = lane >> 4;
  #pragma unroll
  for (int i = 0; i < 4; ++i)
    #pragma unroll
    for (int ii = 0; ii < 4; ++ii){
      int row = mt*128 + wm*64 + 16*i + 4*q + ii;
      float bias = Wbf[row];
      #pragma unroll
      for (int j = 0; j < 4; ++j){
        int col = nt*128 + wn*64 + 16*j + r;
        zb[(size_t)row*HW + col] = f2bf(acc[i][j][ii] + bias);
      }
    }
}

// ---- K7: per-channel BN stats -> scale/shift
__global__ __launch_bounds__(256) void k_bnstats(const unsigned short* __restrict__ z,
    const float* __restrict__ gamf, const float* __restrict__ betf,
    float* __restrict__ scale, float* __restrict__ shift){
  const int o = blockIdx.x, t = threadIdx.x, lane = t & 63, w = t >> 6;
  float sum = 0.f, ss = 0.f;
  for (int b = 0; b < NB; ++b){
    const unsigned short* p = z + ((size_t)b*C_ + o)*HW + t*16;
    #pragma unroll
    for (int it = 0; it < 2; ++it){
      uint4 raw = *(const uint4*)(p + it*8);
      unsigned int wd[4] = {raw.x, raw.y, raw.z, raw.w};
      #pragma unroll
      for (int k = 0; k < 4; ++k){
        float f0 = bf2f((unsigned short)(wd[k] & 0xffff));
        float f1 = bf2f((unsigned short)(wd[k] >> 16));
        sum += f0 + f1; ss += f0*f0 + f1*f1;
      }
    }
  }
  #pragma unroll
  for (int off = 1; off < 64; off <<= 1){
    sum += __shfl_xor(sum, off);
    ss  += __shfl_xor(ss, off);
  }
  __shared__ float r1[4], r2[4];
  if (lane == 0){ r1[w] = sum; r2[w] = ss; }
  __syncthreads();
  if (t == 0){
    float S1 = r1[0]+r1[1]+r1[2]+r1[3];
    float S2 = r2[0]+r2[1]+r2[2]+r2[3];
    const float n = (float)NB * (float)HW;
    float mean = S1 / n;
    float var  = S2 / n - mean*mean;
    float sc = gamf[o] * rsqrtf(var + 1e-5f);
    scale[o] = sc;
    shift[o] = betf[o] - mean*sc;
  }
}

// ---- K8: out = z*scale + shift + x  (dtype per flag)
__global__ __launch_bounds__(256) void k_out(const unsigned short* __restrict__ z,
    const void* __restrict__ xraw, const int* __restrict__ flag,
    const float* __restrict__ scale, const float* __restrict__ shift, void* __restrict__ outraw){
  const bool f32 = (*flag != 0);
  const size_t g = (size_t)blockIdx.x*256 + threadIdx.x;
  const size_t base = g*8;
  const int o = (int)((base >> 12) & (C_ - 1));
  const float sc = scale[o], sh = shift[o];
  uint4 zr = *(const uint4*)(z + base);
  unsigned int zz[4] = {zr.x, zr.y, zr.z, zr.w};
  float zv[8];
  #pragma unroll
  for (int k = 0; k < 4; ++k){
    zv[2*k]   = bf2f((unsigned short)(zz[k] & 0xffff));
    zv[2*k+1] = bf2f((unsigned short)(zz[k] >> 16));
  }
  if (f32){
    const float* x = (const float*)xraw;
    float* out = (float*)outraw;
    f32x4 x0 = *(const f32x4*)(x + base);
    f32x4 x1 = *(const f32x4*)(x + base + 4);
    f32x4 o0, o1;
    #pragma unroll
    for (int k = 0; k < 4; ++k){
      o0[k] = zv[k]*sc + sh + x0[k];
      o1[k] = zv[4+k]*sc + sh + x1[k];
    }
    *(f32x4*)(out + base) = o0;
    *(f32x4*)(out + base + 4) = o1;
  } else {
    const unsigned short* x = (const unsigned short*)xraw;
    unsigned short* out = (unsigned short*)outraw;
    uint4 xr = *(const uint4*)(x + base);
    unsigned int xx[4] = {xr.x, xr.y, xr.z, xr.w};
    unsigned int res[4];
    #pragma unroll
    for (int k = 0; k < 4; ++k){
      float x0 = bf2f((unsigned short)(xx[k] & 0xffff));
      float x1 = bf2f((unsigned short)(xx[k] >> 16));
      res[k] = (unsigned int)f2bf(zv[2*k]*sc + sh + x0)
             | ((unsigned int)f2bf(zv[2*k+1]*sc + sh + x1) << 16);
    }
    uint4 ov; ov.x = res[0]; ov.y = res[1]; ov.z = res[2]; ov.w = res[3];
    *(uint4*)(out + base) = ov;
  }
}

extern "C" void kernel_launch(void* const* d_in, const int* in_sizes, int n_in,
                              void* d_out, int out_size, void* d_ws, size_t ws_size,
                              hipStream_t stream){
  (void)in_sizes; (void)n_in; (void)out_size;
  const void* x   = d_in[0];
  const void* g_w = d_in[1];
  const void* g_b = d_in[2];
  const void* t_w = d_in[3];
  const void* t_b = d_in[4];
  const void* p_w = d_in[5];
  const void* p_b = d_in[6];
  const void* W_w = d_in[7];
  const void* W_b = d_in[8];
  const void* gam = d_in[9];
  const void* bet = d_in[10];
  char* ws = (char*)d_ws;

  constexpr size_t OFF_FLAG = 0;
  constexpr size_t OFF_TWH = OFF_FLAG + 16;
  constexpr size_t OFF_TWL = OFF_TWH + (size_t)CI*C_*2;
  constexpr size_t OFF_PHH = OFF_TWL + (size_t)CI*C_*2;
  constexpr size_t OFF_PHL = OFF_PHH + (size_t)CI*C_*2;
  constexpr size_t OFF_GWC = OFF_PHL + (size_t)CI*C_*2;
  constexpr size_t OFF_WWC = OFF_GWC + (size_t)CI*C_*2;
  constexpr size_t OFF_BIA = OFF_WWC + (size_t)C_*CI*2;
  constexpr size_t OFF_GH = OFF_BIA + 2304*4;
  constexpr size_t OFF_GL = OFF_GH + (size_t)NB*C_*C_*2;
  constexpr size_t OFF_S  = OFF_GL + (size_t)NB*C_*C_*2;
  constexpr size_t OFF_U  = OFF_S  + (size_t)NB*C_*4;
  constexpr size_t OFF_V  = OFF_U  + (size_t)NB*CI*4;
  constexpr size_t OFF_GT = OFF_V  + (size_t)NB*CI*4;
  constexpr size_t OFF_TH = OFF_GT + (size_t)NB*HW*CI*2;
  constexpr size_t OFF_TL = OFF_TH + (size_t)NB*CI*C_*2;
  constexpr size_t OFF_F  = OFF_TL + (size_t)NB*CI*C_*2;
  constexpr size_t OFF_SM = OFF_F  + (size_t)NB*CI*CI*4;
  constexpr size_t OFF_M2 = OFF_SM + (size_t)NB*CI*CI*2;
  constexpr size_t OFF_Z  = OFF_M2 + (size_t)NB*C_*CI*2;
  constexpr size_t OFF_SC = OFF_Z  + (size_t)NB*C_*HW*2;
  constexpr size_t OFF_SH = OFF_SC + (size_t)C_*4;
  constexpr size_t OFF_XH = OFF_SH + (size_t)C_*4;
  constexpr size_t TOTAL  = OFF_XH + (size_t)NB*C_*HW*2;
  // aliases (disjoint lifetimes):
  //   Gp (fp32 Gram partials, 16*10*4*16384*4 = 41943040 B) over [gT|Th|Tl] (33554432+4194304*2
  //     = 41943040 B): Gp dead after k_gred; gT/Th/Tl written after k_gred.
  //   xl (bf16 lo of x, NB*C_*HW*2 = 67108864 B) over Z (same size): xl dead after k_gram;
  //     z written by k_z much later.
  static_assert((size_t)NB*10*KSPLIT*16384*4 ==
                (size_t)NB*HW*CI*2 + 2*(size_t)NB*CI*C_*2, "Gp alias size");
  if (ws_size < TOTAL) return;

  int* flag = (int*)(ws + OFF_FLAG);
  unsigned short* twh = (unsigned short*)(ws + OFF_TWH);
  unsigned short* twl = (unsigned short*)(ws + OFF_TWL);
  unsigned short* phh = (unsigned short*)(ws + OFF_PHH);
  unsigned short* phl = (unsigned short*)(ws + OFF_PHL);
  unsigned short* gwc = (unsigned short*)(ws + OFF_GWC);
  unsigned short* Wwc = (unsigned short*)(ws + OFF_WWC);
  float* biasf = (float*)(ws + OFF_BIA);
  unsigned short* Gh = (unsigned short*)(ws + OFF_GH);
  unsigned short* Gl = (unsigned short*)(ws + OFF_GL);
  float* s  = (float*)(ws + OFF_S);
  float* u  = (float*)(ws + OFF_U);
  float* v  = (float*)(ws + OFF_V);
  unsigned short* gT = (unsigned short*)(ws + OFF_GT);
  unsigned short* Th = (unsigned short*)(ws + OFF_TH);
  unsigned short* Tl = (unsigned short*)(ws + OFF_TL);
  float* f  = (float*)(ws + OFF_F);
  unsigned short* Sm = (unsigned short*)(ws + OFF_SM);
  unsigned short* M2 = (unsigned short*)(ws + OFF_M2);
  unsigned short* z  = (unsigned short*)(ws + OFF_Z);
  float* scale = (float*)(ws + OFF_SC);
  float* shift = (float*)(ws + OFF_SH);
  unsigned short* xh = (unsigned short*)(ws + OFF_XH);
  unsigned short* xl = (unsigned short*)(ws + OFF_Z);   // alias over Z
  float* Gp = (float*)(ws + OFF_GT);                    // alias over gT/Th/Tl

  float* gbf = biasf;          // 256
  float* tbf = biasf + 256;    // 256
  float* pbf = biasf + 512;    // 256
  float* Wbf = biasf + 768;    // 512
  float* gamf = biasf + 1280;  // 512
  float* betf = biasf + 1792;  // 512

  dim3 blk(256);
  k_detect <<<dim3(1),          blk, 0, stream>>>((const unsigned short*)x, flag);
  k_wconv  <<<dim3(2057),       blk, 0, stream>>>(t_w, p_w, g_w, W_w, g_b, t_b, p_b, W_b,
                                                  gam, bet, flag, twh, twl, phh, phl, gwc, Wwc, biasf);
  k_xconv  <<<dim3(NB*C_),      blk, 0, stream>>>(x, flag, xh, xl, s);
  k_gram   <<<dim3(10, KSPLIT, NB), blk, 0, stream>>>(x, xh, xl, flag, Gp);
  k_gred   <<<dim3(4, 4, NB),   blk, 0, stream>>>(Gp, Gh, Gl);
  k_gconv  <<<dim3(32, 2, NB),  blk, 0, stream>>>(x, flag, xh, gwc, gbf, gT);
  k_T      <<<dim3(4, 2, NB),   blk, 0, stream>>>(twh, twl, flag, Gh, Gl, Th, Tl);
  k_uv     <<<dim3(NB),         blk, 0, stream>>>(twh, twl, phh, phl, s, u, v);
  k_f      <<<dim3(2, 2, NB),   blk, 0, stream>>>(Th, Tl, phh, phl, flag, f);
  k_softmax<<<dim3(64, NB),     blk, 0, stream>>>(f, u, v, tbf, pbf, Sm);
  k_M2     <<<dim3(2, 4, NB),   blk, 0, stream>>>(Wwc, Sm, M2);
  k_z      <<<dim3(32, 4, NB),  blk, 0, stream>>>(M2, gT, Wbf, z);
  k_bnstats<<<dim3(C_),         blk, 0, stream>>>(z, gamf, betf, scale, shift);
  k_out    <<<dim3(16384),      blk, 0, stream>>>(z, x, flag, scale, shift, d_out);
}

// Round 3
// 769.910 us; speedup vs baseline: 1.1122x; 1.1122x over previous
//
#include <hip/hip_runtime.h>

typedef __bf16 bf16x8 __attribute__((ext_vector_type(8)));
typedef float f32x4 __attribute__((ext_vector_type(4)));

#define LDK 40   // padded LDS k-stride (bf16 elems) for register-staged kernels
#define NB 16
#define C_ 512
#define CI 256
#define HW 4096
#define KSPLIT 4
#define KCHUNK (HW / KSPLIT)

__device__ __forceinline__ float bf2f(unsigned short u){
  union { unsigned int u; float f; } c; c.u = ((unsigned int)u) << 16; return c.f;
}
__device__ __forceinline__ unsigned short f2bf(float f){
  union { float f; unsigned int u; } c; c.f = f;
  unsigned int u = c.u + 0x7fffu + ((c.u >> 16) & 1u);
  return (unsigned short)(u >> 16);
}
__device__ __forceinline__ float read_val(const void* p, int i, bool f32){
  return f32 ? ((const float*)p)[i] : bf2f(((const unsigned short*)p)[i]);
}

// ---- staging helpers (256 threads) ----

// 128 rows x 32 k bf16 row-major -> LDS [row][k] (padded LDK)
__device__ __forceinline__ void stage_rm(const unsigned short* __restrict__ src, int stride,
                                         unsigned short* dst, int t){
  #pragma unroll
  for (int it = 0; it < 2; ++it){
    int idx = t + it*256;
    int row = idx >> 2;
    int ko  = (idx & 3) * 8;
    *(uint4*)(dst + row*LDK + ko) = *(const uint4*)(src + (size_t)row*stride + ko);
  }
}

// 32 src-rows x 128 src-cols bf16 -> LDS transposed dst[col][row]
__device__ __forceinline__ void stage_tr(const unsigned short* __restrict__ src, int stride,
                                         unsigned short* dst, int t){
  #pragma unroll
  for (int it = 0; it < 2; ++it){
    int idx = t + it*256;
    int row = idx >> 4;              // 0..31
    int co  = (idx & 15) * 8;
    uint4 vv = *(const uint4*)(src + (size_t)row*stride + co);
    unsigned short e[8]; *(uint4*)e = vv;
    #pragma unroll
    for (int k = 0; k < 8; ++k) dst[(co + k)*LDK + row] = e[k];
  }
}

// one 32-wide k-step on padded-LDK tiles: wave (wm,wn) covers 64x64, 16 mfma
__device__ __forceinline__ void mfma_step(const unsigned short* As, const unsigned short* Bs,
                                          f32x4 acc[4][4], int wm, int wn, int lane){
  const int r = lane & 15, q = lane >> 4;
  bf16x8 a[4], b[4];
  #pragma unroll
  for (int i = 0; i < 4; ++i)
    a[i] = *(const bf16x8*)(As + (wm*64 + 16*i + r)*LDK + 8*q);
  #pragma unroll
  for (int j = 0; j < 4; ++j)
    b[j] = *(const bf16x8*)(Bs + (wn*64 + 16*j + r)*LDK + 8*q);
  #pragma unroll
  for (int i = 0; i < 4; ++i)
    #pragma unroll
    for (int j = 0; j < 4; ++j)
      acc[i][j] = __builtin_amdgcn_mfma_f32_16x16x32_bf16(a[i], b[j], acc[i][j], 0, 0, 0);
}

// ---- async global->LDS (16B per lane, wave-uniform LDS base) ----
// NOTE: builtin's global-ptr param is non-const -> const_cast, then addrspacecast.
__device__ __forceinline__ void gload16(const unsigned short* g, unsigned short* l){
  __builtin_amdgcn_global_load_lds(
      (__attribute__((address_space(1))) void*)const_cast<unsigned short*>(g),
      (__attribute__((address_space(3))) void*)l, 16, 0, 0);
}

// stage 128 rows x 64 elems into LINEAR LDS [128][64] via global_load_lds.
// Source pre-swizzle: LDS(row, pchunk) holds src chunk (pchunk ^ (row&7)).
// 4 instrs per wave; wave w covers rows 32w..32w+31.
__device__ __forceinline__ void gstage(const unsigned short* __restrict__ src, size_t rstride,
                                       unsigned short* buf, int w, int lane){
  const int ro = lane >> 3;               // row within 8-row group
  const int sc = (lane & 7) ^ ro;         // pre-swizzled source chunk
  const unsigned short* s0 = src + (size_t)ro*rstride + sc*8;
  unsigned short* l0 = buf + (size_t)(w*32)*64;
  #pragma unroll
  for (int i = 0; i < 4; ++i)
    gload16(s0 + (size_t)(w*32 + i*8)*rstride, l0 + i*8*64);
}

// ---- K0: dtype detect. fp32 inputs read as bf16 halves contain exp==0xFF patterns.
__global__ __launch_bounds__(256) void k_detect(const unsigned short* __restrict__ x, int* flag){
  const int t = threadIdx.x;
  int cnt = 0;
  for (int i = t; i < 65536; i += 256){
    unsigned short u = x[i];
    if (((u >> 7) & 0xFF) == 0xFF) cnt++;
  }
  __shared__ int red[256];
  red[t] = cnt; __syncthreads();
  for (int s2 = 128; s2 > 0; s2 >>= 1){
    if (t < s2) red[t] += red[t + s2];
    __syncthreads();
  }
  if (t == 0) flag[0] = (red[0] > 0) ? 1 : 0;
}

// ---- K0b: convert weights to canonical buffers
__global__ __launch_bounds__(256) void k_wconv(const void* tw, const void* pw, const void* gw,
    const void* Ww, const void* gb, const void* tb, const void* pb, const void* Wb,
    const void* gam, const void* bet, const int* __restrict__ flag,
    unsigned short* twh, unsigned short* twl, unsigned short* phh, unsigned short* phl,
    unsigned short* gwc, unsigned short* Wwc, float* biasf){
  const bool f32 = (*flag != 0);
  const int bid = blockIdx.x, t = threadIdx.x;
  if (bid < 2048){
    const int seg = bid >> 9;
    const int i = (bid & 511)*256 + t;
    if (seg == 0){
      float w = read_val(tw, i, f32);
      unsigned short h = f2bf(w);
      twh[i] = h; twl[i] = f2bf(w - bf2f(h));
    } else if (seg == 1){
      float w = read_val(pw, i, f32);
      unsigned short h = f2bf(w);
      phh[i] = h; phl[i] = f2bf(w - bf2f(h));
    } else if (seg == 2){
      gwc[i] = f2bf(read_val(gw, i, f32));
    } else {
      Wwc[i] = f2bf(read_val(Ww, i, f32));
    }
  } else {
    const int i = (bid - 2048)*256 + t;
    if (i < 2304){
      float v;
      if      (i <  256) v = read_val(gb,  i,        f32);
      else if (i <  512) v = read_val(tb,  i - 256,  f32);
      else if (i <  768) v = read_val(pb,  i - 512,  f32);
      else if (i < 1280) v = read_val(Wb,  i - 768,  f32);
      else if (i < 1792) v = read_val(gam, i - 1280, f32);
      else               v = read_val(bet, i - 1792, f32);
      biasf[i] = v;
    }
  }
}

// ---- K0c: x fp32 -> xq interleaved hi/lo bf16 chunks ([c][kchunk][32 hi | 32 lo]) + rowsums s.
//      bf16 input: rowsums only (x used directly downstream).
__global__ __launch_bounds__(256) void k_xconv(const void* __restrict__ xraw,
    const int* __restrict__ flag, unsigned short* __restrict__ xq, float* __restrict__ s){
  const bool f32 = (*flag != 0);
  const int bc = blockIdx.x, t = threadIdx.x;   // bc = b*C_ + c
  float sum = 0.f;
  if (f32){
    const float* xr = (const float*)xraw + (size_t)bc*HW;
    unsigned short* oq = xq + (size_t)bc*8192;
    #pragma unroll
    for (int it = 0; it < 4; ++it){
      const int off = it*1024 + t*4;
      f32x4 v = *(const f32x4*)(xr + off);
      unsigned int wh[2], wl[2];
      #pragma unroll
      for (int k = 0; k < 2; ++k){
        unsigned short h0 = f2bf(v[2*k]),   h1 = f2bf(v[2*k+1]);
        unsigned short l0 = f2bf(v[2*k]   - bf2f(h0));
        unsigned short l1 = f2bf(v[2*k+1] - bf2f(h1));
        wh[k] = (unsigned int)h0 | ((unsigned int)h1 << 16);
        wl[k] = (unsigned int)l0 | ((unsigned int)l1 << 16);
      }
      sum += v[0] + v[1] + v[2] + v[3];
      const int qb = (off >> 5)*64 + (off & 31);
      *(uint2*)(oq + qb)      = make_uint2(wh[0], wh[1]);
      *(uint2*)(oq + qb + 32) = make_uint2(wl[0], wl[1]);
    }
  } else {
    const unsigned short* xr = (const unsigned short*)xraw + (size_t)bc*HW;
    #pragma unroll
    for (int it = 0; it < 2; ++it){
      const int off = it*2048 + t*8;
      uint4 raw = *(const uint4*)(xr + off);
      unsigned int wd[4] = {raw.x, raw.y, raw.z, raw.w};
      #pragma unroll
      for (int k = 0; k < 4; ++k)
        sum += bf2f((unsigned short)(wd[k] & 0xffff)) + bf2f((unsigned short)(wd[k] >> 16));
    }
  }
  #pragma unroll
  for (int off = 1; off < 64; off <<= 1) sum += __shfl_xor(sum, off);
  __shared__ float r1[4];
  if ((t & 63) == 0) r1[t >> 6] = sum;
  __syncthreads();
  if (t == 0) s[bc] = r1[0] + r1[1] + r1[2] + r1[3];
}

// ---- K1a: partial Gram, upper tiles (bm<=bn), k-split x4.
// global_load_lds + swizzled linear LDS + double buffer + 1 barrier/step.
// Gp layout: [b][tile(10)][ks(4)][128][128] fp32
__global__ __launch_bounds__(256) void k_gram(const void* __restrict__ xraw,
    const unsigned short* __restrict__ xq, const int* __restrict__ flag,
    float* __restrict__ Gp){
  const bool f32 = (*flag != 0);
  const int b = blockIdx.z, ks = blockIdx.y, tile = blockIdx.x;
  int bm, bn;
  if      (tile < 4){ bm = 0; bn = tile; }
  else if (tile < 7){ bm = 1; bn = tile - 3; }
  else if (tile < 9){ bm = 2; bn = tile - 5; }
  else              { bm = 3; bn = 3; }
  const int t = threadIdx.x, lane = t & 63, w = t >> 6, wm = w >> 1, wn = w & 1;
  __shared__ __align__(16) unsigned short Abuf[2][128*64];
  __shared__ __align__(16) unsigned short Bbuf[2][128*64];
  const bool diag = (bm == bn);
  const unsigned short* srcA;
  const unsigned short* srcB;
  size_t rstride;
  int nsteps;
  if (f32){
    const unsigned short* xb = xq + (size_t)b*C_*8192;
    srcA = xb + (size_t)(bm*128)*8192 + (size_t)ks*(KCHUNK/32)*64;
    srcB = xb + (size_t)(bn*128)*8192 + (size_t)ks*(KCHUNK/32)*64;
    rstride = 8192; nsteps = KCHUNK/32;      // one chunk (32 real k, hi|lo) per step
  } else {
    const unsigned short* xb = (const unsigned short*)xraw + (size_t)b*C_*HW;
    srcA = xb + (size_t)(bm*128)*HW + ks*KCHUNK;
    srcB = xb + (size_t)(bn*128)*HW + ks*KCHUNK;
    rstride = HW; nsteps = KCHUNK/64;        // 64 real k per step
  }
  f32x4 acc[4][4] = {};
  const int r = lane & 15, q = lane >> 4;
  const int rx = r & 7;
  const int c0 = q ^ rx;          // physical chunk for logical ksub=0
  const int c1 = (4 + q) ^ rx;    // physical chunk for logical ksub=1

  gstage(srcA, rstride, Abuf[0], w, lane);
  if (!diag) gstage(srcB, rstride, Bbuf[0], w, lane);
  __syncthreads();

  int cur = 0;
  for (int st = 0; st < nsteps; ++st){
    if (st + 1 < nsteps){
      gstage(srcA + (size_t)(st+1)*64, rstride, Abuf[cur^1], w, lane);
      if (!diag) gstage(srcB + (size_t)(st+1)*64, rstride, Bbuf[cur^1], w, lane);
    }
    const unsigned short* A = Abuf[cur];
    const unsigned short* B = diag ? Abuf[cur] : Bbuf[cur];
    bf16x8 a0[4], a1[4], b0[4], b1[4];
    #pragma unroll
    for (int i = 0; i < 4; ++i){
      const unsigned short* ap = A + (size_t)(wm*64 + 16*i + r)*64;
      a0[i] = *(const bf16x8*)(ap + c0*8);
      a1[i] = *(const bf16x8*)(ap + c1*8);
    }
    #pragma unroll
    for (int j = 0; j < 4; ++j){
      const unsigned short* bp = B + (size_t)(wn*64 + 16*j + r)*64;
      b0[j] = *(const bf16x8*)(bp + c0*8);
      b1[j] = *(const bf16x8*)(bp + c1*8);
    }
    if (f32){
      // chunk = [32 hi | 32 lo]: hh + hl + lh
      #pragma unroll
      for (int i = 0; i < 4; ++i)
        #pragma unroll
        for (int j = 0; j < 4; ++j){
          acc[i][j] = __builtin_amdgcn_mfma_f32_16x16x32_bf16(a0[i], b0[j], acc[i][j], 0, 0, 0);
          acc[i][j] = __builtin_amdgcn_mfma_f32_16x16x32_bf16(a0[i], b1[j], acc[i][j], 0, 0, 0);
          acc[i][j] = __builtin_amdgcn_mfma_f32_16x16x32_bf16(a1[i], b0[j], acc[i][j], 0, 0, 0);
        }
    } else {
      // two independent 32-k halves
      #pragma unroll
      for (int i = 0; i < 4; ++i)
        #pragma unroll
        for (int j = 0; j < 4; ++j){
          acc[i][j] = __builtin_amdgcn_mfma_f32_16x16x32_bf16(a0[i], b0[j], acc[i][j], 0, 0, 0);
          acc[i][j] = __builtin_amdgcn_mfma_f32_16x16x32_bf16(a1[i], b1[j], acc[i][j], 0, 0, 0);
        }
    }
    __syncthreads();
    cur ^= 1;
  }
  float* Gt = Gp + (((size_t)b*10 + tile)*KSPLIT + ks)*16384;
  #pragma unroll
  for (int i = 0; i < 4; ++i)
    #pragma unroll
    for (int j = 0; j < 4; ++j)
      #pragma unroll
      for (int ii = 0; ii < 4; ++ii){
        int row = wm*64 + 16*i + 4*q + ii;
        int col = wn*64 + 16*j + r;
        Gt[row*128 + col] = acc[i][j][ii];
      }
}

// ---- K1c: reduce k-split partials, mirror across diagonal, emit Gh/Gl bf16
__global__ __launch_bounds__(256) void k_gred(const float* __restrict__ Gp,
    unsigned short* __restrict__ Gh, unsigned short* __restrict__ Gl){
  const int b = blockIdx.z, bmO = blockIdx.y, bnO = blockIdx.x, t = threadIdx.x;
  const int lo = bmO < bnO ? bmO : bnO;
  const int hi = bmO < bnO ? bnO : bmO;
  const int tile = (lo == 0) ? hi : (lo == 1) ? 3 + hi : (lo == 2) ? 5 + hi : 9;
  const float* src = Gp + ((size_t)b*10 + tile)*KSPLIT*16384;
  unsigned short* ghB = Gh + (size_t)b*C_*C_;
  unsigned short* glB = Gl + (size_t)b*C_*C_;
  if (bmO <= bnO){
    #pragma unroll
    for (int i = 0; i < 16; ++i){
      const int off = i*1024 + t*4;
      f32x4 v = *(const f32x4*)(src + off);
      #pragma unroll
      for (int ks = 1; ks < KSPLIT; ++ks){
        f32x4 u2 = *(const f32x4*)(src + ks*16384 + off);
        v[0] += u2[0]; v[1] += u2[1]; v[2] += u2[2]; v[3] += u2[3];
      }
      const int row = off >> 7, col = off & 127;
      unsigned int wh[2], wl[2];
      #pragma unroll
      for (int k = 0; k < 2; ++k){
        unsigned short h0 = f2bf(v[2*k]),   h1 = f2bf(v[2*k+1]);
        unsigned short l0 = f2bf(v[2*k]   - bf2f(h0));
        unsigned short l1 = f2bf(v[2*k+1] - bf2f(h1));
        wh[k] = (unsigned int)h0 | ((unsigned int)h1 << 16);
        wl[k] = (unsigned int)l0 | ((unsigned int)l1 << 16);
      }
      size_t o = (size_t)(bmO*128 + row)*C_ + bnO*128 + col;
      *(uint2*)(ghB + o) = make_uint2(wh[0], wh[1]);
      *(uint2*)(glB + o) = make_uint2(wl[0], wl[1]);
    }
  } else {
    __shared__ float ldz[32*129];
    const int rr = t >> 1, cseg = (t & 1)*16;
    const int orl = t >> 3, oseg = (t & 7)*16;
    for (int cc = 0; cc < 4; ++cc){
      float vals[16];
      #pragma unroll
      for (int j = 0; j < 4; ++j){
        const int so = rr*128 + cc*32 + cseg + j*4;
        f32x4 v = *(const f32x4*)(src + so);
        #pragma unroll
        for (int ks = 1; ks < KSPLIT; ++ks){
          f32x4 u2 = *(const f32x4*)(src + ks*16384 + so);
          v[0] += u2[0]; v[1] += u2[1]; v[2] += u2[2]; v[3] += u2[3];
        }
        vals[4*j] = v[0]; vals[4*j+1] = v[1]; vals[4*j+2] = v[2]; vals[4*j+3] = v[3];
      }
      __syncthreads();
      #pragma unroll
      for (int e = 0; e < 16; ++e) ldz[(cseg + e)*129 + rr] = vals[e];
      __syncthreads();
      unsigned int wh[8], wl[8];
      #pragma unroll
      for (int k = 0; k < 8; ++k){
        float f0 = ldz[orl*129 + oseg + 2*k];
        float f1 = ldz[orl*129 + oseg + 2*k + 1];
        unsigned short h0 = f2bf(f0), h1 = f2bf(f1);
        unsigned short l0 = f2bf(f0 - bf2f(h0)), l1 = f2bf(f1 - bf2f(h1));
        wh[k] = (unsigned int)h0 | ((unsigned int)h1 << 16);
        wl[k] = (unsigned int)l0 | ((unsigned int)l1 << 16);
      }
      size_t o = (size_t)(bmO*128 + cc*32 + orl)*C_ + bnO*128 + oseg;
      *(uint4*)(ghB + o)     = make_uint4(wh[0], wh[1], wh[2], wh[3]);
      *(uint4*)(ghB + o + 8) = make_uint4(wh[4], wh[5], wh[6], wh[7]);
      *(uint4*)(glB + o)     = make_uint4(wl[0], wl[1], wl[2], wl[3]);
      *(uint4*)(glB + o + 8) = make_uint4(wl[4], wl[5], wl[6], wl[7]);
    }
  }
}

// ---- K2: T[b] = theta_w @ G[b]
__global__ __launch_bounds__(256) void k_T(const unsigned short* __restrict__ twh,
    const unsigned short* __restrict__ twl, const int* __restrict__ flag,
    const unsigned short* __restrict__ Gh, const unsigned short* __restrict__ Gl,
    unsigned short* __restrict__ Th, unsigned short* __restrict__ Tl){
  const bool f32 = (*flag != 0);
  const int b = blockIdx.z, nt = blockIdx.x, mt = blockIdx.y;
  const int t = threadIdx.x, lane = t & 63, w = t >> 6, wm = w >> 1, wn = w & 1;
  __shared__ unsigned short Ath[128*LDK];
  __shared__ unsigned short Atl[128*LDK];
  __shared__ unsigned short Bh[128*LDK];
  __shared__ unsigned short Bl[128*LDK];
  const unsigned short* Ghb = Gh + (size_t)b*C_*C_;
  const unsigned short* Glb = Gl + (size_t)b*C_*C_;
  f32x4 acc[4][4] = {};
  for (int k0 = 0; k0 < C_; k0 += 32){
    stage_rm(twh + (size_t)mt*128*C_ + k0, C_, Ath, t);
    if (f32) stage_rm(twl + (size_t)mt*128*C_ + k0, C_, Atl, t);
    stage_rm(Ghb + (size_t)nt*128*C_ + k0, C_, Bh, t);
    stage_rm(Glb + (size_t)nt*128*C_ + k0, C_, Bl, t);
    __syncthreads();
    mfma_step(Ath, Bh, acc, wm, wn, lane);
    mfma_step(Ath, Bl, acc, wm, wn, lane);
    if (f32) mfma_step(Atl, Bh, acc, wm, wn, lane);
    __syncthreads();
  }
  unsigned short* Thb = Th + (size_t)b*CI*C_;
  unsigned short* Tlb = Tl + (size_t)b*CI*C_;
  const int r = lane & 15, q = lane >> 4;
  #pragma unroll
  for (int i = 0; i < 4; ++i)
    #pragma unroll
    for (int j = 0; j < 4; ++j)
      #pragma unroll
      for (int ii = 0; ii < 4; ++ii){
        int row = mt*128 + wm*64 + 16*i + 4*q + ii;
        int col = nt*128 + wn*64 + 16*j + r;
        float vv = acc[i][j][ii];
        unsigned short h = f2bf(vv);
        Thb[(size_t)row*C_ + col] = h;
        Tlb[(size_t)row*C_ + col] = f2bf(vv - bf2f(h));
      }
}

// ---- K3: f[b] = (Th+Tl) @ phi^T
__global__ __launch_bounds__(256) void k_f(const unsigned short* __restrict__ Th,
    const unsigned short* __restrict__ Tl, const unsigned short* __restrict__ phh,
    const unsigned short* __restrict__ phl, const int* __restrict__ flag,
    float* __restrict__ f){
  const bool f32 = (*flag != 0);
  const int b = blockIdx.z, nt = blockIdx.x, mt = blockIdx.y;
  const int t = threadIdx.x, lane = t & 63, w = t >> 6, wm = w >> 1, wn = w & 1;
  __shared__ unsigned short ATh[128*LDK];
  __shared__ unsigned short ATl[128*LDK];
  __shared__ unsigned short Bph[128*LDK];
  __shared__ unsigned short Bpl[128*LDK];
  f32x4 acc[4][4] = {};
  const unsigned short* Thb = Th + (size_t)b*CI*C_;
  const unsigned short* Tlb = Tl + (size_t)b*CI*C_;
  for (int k0 = 0; k0 < C_; k0 += 32){
    stage_rm(Thb + (size_t)mt*128*C_ + k0, C_, ATh, t);
    stage_rm(Tlb + (size_t)mt*128*C_ + k0, C_, ATl, t);
    stage_rm(phh + (size_t)nt*128*C_ + k0, C_, Bph, t);
    if (f32) stage_rm(phl + (size_t)nt*128*C_ + k0, C_, Bpl, t);
    __syncthreads();
    mfma_step(ATh, Bph, acc, wm, wn, lane);
    mfma_step(ATl, Bph, acc, wm, wn, lane);
    if (f32) mfma_step(ATh, Bpl, acc, wm, wn, lane);
    __syncthreads();
  }
  float* fb = f + (size_t)b*CI*CI;
  const int r = lane & 15, q = lane >> 4;
  #pragma unroll
  for (int i = 0; i < 4; ++i)
    #pragma unroll
    for (int j = 0; j < 4; ++j)
      #pragma unroll
      for (int ii = 0; ii < 4; ++ii){
        int row = mt*128 + wm*64 + 16*i + 4*q + ii;
        int col = nt*128 + wn*64 + 16*j + r;
        fb[(size_t)row*CI + col] = acc[i][j][ii];
      }
}

// u = theta_w @ s, v = phi_w @ s
__global__ __launch_bounds__(256) void k_uv(const unsigned short* __restrict__ twh,
    const unsigned short* __restrict__ twl, const unsigned short* __restrict__ phh,
    const unsigned short* __restrict__ phl, const float* __restrict__ s,
    float* __restrict__ u, float* __restrict__ v){
  const int b = blockIdx.x, c = threadIdx.x;
  __shared__ float sl[C_];
  sl[c] = s[(size_t)b*C_ + c];
  sl[c + 256] = s[(size_t)b*C_ + c + 256];
  __syncthreads();
  float su = 0.f, sv = 0.f;
  for (int e = 0; e < C_; ++e){
    su += (bf2f(twh[(size_t)c*C_ + e]) + bf2f(twl[(size_t)c*C_ + e])) * sl[e];
    sv += (bf2f(phh[(size_t)c*C_ + e]) + bf2f(phl[(size_t)c*C_ + e])) * sl[e];
  }
  u[(size_t)b*CI + c] = su;
  v[(size_t)b*CI + c] = sv;
}

// ---- K4: softmax rows of f (+ rank-1 bias corrections), write S bf16
__global__ __launch_bounds__(256) void k_softmax(const float* __restrict__ f,
    const float* __restrict__ u, const float* __restrict__ v,
    const float* __restrict__ tbf, const float* __restrict__ pbf,
    unsigned short* __restrict__ S){
  const int b = blockIdx.y;
  const int c = blockIdx.x*4 + (threadIdx.x >> 6);
  const int lane = threadIdx.x & 63;
  const float* fr = f + ((size_t)b*CI + c)*CI;
  f32x4 val = *(const f32x4*)(fr + lane*4);
  const float uc = u[(size_t)b*CI + c];
  const float tbc = tbf[c];
  float vv[4];
  #pragma unroll
  for (int k = 0; k < 4; ++k){
    int d = lane*4 + k;
    float pbd = pbf[d];
    vv[k] = val[k] + uc*pbd + tbc*(v[(size_t)b*CI + d] + 4096.0f*pbd);
  }
  float mx = fmaxf(fmaxf(vv[0], vv[1]), fmaxf(vv[2], vv[3]));
  #pragma unroll
  for (int off = 1; off < 64; off <<= 1) mx = fmaxf(mx, __shfl_xor(mx, off));
  float e[4], sum = 0.f;
  #pragma unroll
  for (int k = 0; k < 4; ++k){ e[k] = expf(vv[k] - mx); sum += e[k]; }
  #pragma unroll
  for (int off = 1; off < 64; off <<= 1) sum += __shfl_xor(sum, off);
  float inv = 1.0f / sum;
  uint2 pack;
  pack.x = (unsigned int)f2bf(e[0]*inv) | ((unsigned int)f2bf(e[1]*inv) << 16);
  pack.y = (unsigned int)f2bf(e[2]*inv) | ((unsigned int)f2bf(e[3]*inv) << 16);
  *(uint2*)(S + ((size_t)b*CI + c)*CI + lane*4) = pack;
}

// ---- K5: M2[b] = W_w @ S[b]
__global__ __launch_bounds__(256) void k_M2(const unsigned short* __restrict__ Wwc,
                                            const unsigned short* __restrict__ S,
                                            unsigned short* __restrict__ M2){
  const int b = blockIdx.z, nt = blockIdx.x, mt = blockIdx.y;
  const int t = threadIdx.x, lane = t & 63, w = t >> 6, wm = w >> 1, wn = w & 1;
  __shared__ unsigned short As[128*LDK];
  __shared__ unsigned short Bs[128*LDK];
  f32x4 acc[4][4] = {};
  for (int k0 = 0; k0 < CI; k0 += 32){
    stage_rm(Wwc + (size_t)mt*128*CI + k0, CI, As, t);
    stage_tr(S + (size_t)b*CI*CI + (size_t)k0*CI + nt*128, CI, Bs, t);
    __syncthreads();
    mfma_step(As, Bs, acc, wm, wn, lane);
    __syncthreads();
  }
  unsigned short* M2b = M2 + (size_t)b*C_*CI;
  const int r = lane & 15, q = lane >> 4;
  #pragma unroll
  for (int i = 0; i < 4; ++i)
    #pragma unroll
    for (int j = 0; j < 4; ++j)
      #pragma unroll
      for (int ii = 0; ii < 4; ++ii){
        int row = mt*128 + wm*64 + 16*i + 4*q + ii;
        int col = nt*128 + wn*64 + 16*j + r;
        M2b[(size_t)row*CI + col] = f2bf(acc[i][j][ii]);
      }
}

// ---- K5b: Wg[b] = M2[b] @ gw   (512x512 per batch; fuses the g-conv into k_zW)
__global__ __launch_bounds__(256) void k_Wg(const unsigned short* __restrict__ M2,
                                            const unsigned short* __restrict__ gwc,
                                            unsigned short* __restrict__ Wg){
  const int b = blockIdx.z, nt = blockIdx.x, mt = blockIdx.y;
  const int t = threadIdx.x, lane = t & 63, w = t >> 6, wm = w >> 1, wn = w & 1;
  __shared__ unsigned short As[128*LDK];
  __shared__ unsigned short Bs[128*LDK];
  const unsigned short* M2b = M2 + (size_t)b*C_*CI;
  f32x4 acc[4][4] = {};
  for (int k0 = 0; k0 < CI; k0 += 32){
    stage_rm(M2b + (size_t)mt*128*CI + k0, CI, As, t);
    stage_tr(gwc + (size_t)k0*C_ + nt*128, C_, Bs, t);   // gw^T tile: [e][ci]
    __syncthreads();
    mfma_step(As, Bs, acc, wm, wn, lane);
    __syncthreads();
  }
  unsigned short* Wgb = Wg + (size_t)b*C_*C_;
  const int r = lane & 15, q = lane >> 4;
  #pragma unroll
  for (int i = 0; i < 4; ++i)
    #pragma unroll
    for (int j = 0; j < 4; ++j)
      #pragma unroll
      for (int ii = 0; ii < 4; ++ii){
        int row = mt*128 + wm*64 + 16*i + 4*q + ii;
        int col = nt*128 + wn*64 + 16*j + r;
        Wgb[(size_t)row*C_ + col] = f2bf(acc[i][j][ii]);
      }
}

// ---- K5c: bias2[b][c] = M2[b] @ g_b + W_b
__global__ __launch_bounds__(256) void k_bias2(const unsigned short* __restrict__ M2,
    const float* __restrict__ gbf, const float* __restrict__ Wbf, float* __restrict__ b2){
  const int b = blockIdx.x, t = threadIdx.x;
  __shared__ float gs[CI];
  gs[t] = gbf[t];
  __syncthreads();
  #pragma unroll
  for (int cc = 0; cc < 2; ++cc){
    int c = cc*256 + t;
    const unsigned short* row = M2 + (size_t)b*C_*CI + (size_t)c*CI;
    float sv = 0.f;
    for (int ci = 0; ci < CI; ++ci) sv += bf2f(row[ci]) * gs[ci];
    b2[(size_t)b*C_ + c] = sv + Wbf[c];
  }
}

// ---- K6: z[b] = Wg[b] @ x[b] + bias2   (8 waves, 512x128 output tile per block)
__global__ __launch_bounds__(512) void k_zW(const unsigned short* __restrict__ Wg,
    const void* __restrict__ xraw, const unsigned short* __restrict__ xq,
    const int* __restrict__ flag, const float* __restrict__ bias2,
    unsigned short* __restrict__ z){
  const bool f32 = (*flag != 0);
  const int b = blockIdx.z, hwp = blockIdx.x;
  const int t = threadIdx.x, lane = t & 63, w = t >> 6;   // 8 waves
  const int wm = w >> 1, wn = w & 1;                      // wm: 128-row group, wn: 64-col group
  __shared__ __align__(16) unsigned short As[512*LDK];    // Wg k-slice: 512 rows x 32 e
  __shared__ __align__(16) unsigned short Bs[128*LDK];    // x^T tile: 128 hw x 32 e
  const unsigned short* Wgb = Wg + (size_t)b*C_*C_;
  const int hw0 = hwp*128;
  f32x4 acc[8][4] = {};
  for (int k0 = 0; k0 < C_; k0 += 32){
    // A: 512 rows x 32 k
    #pragma unroll
    for (int it = 0; it < 4; ++it){
      int idx = t + it*512;
      int row = idx >> 2, ko = (idx & 3)*8;
      *(uint4*)(As + row*LDK + ko) = *(const uint4*)(Wgb + (size_t)row*C_ + k0 + ko);
    }
    // B: transpose-stage 32 e-rows x 128 hw-cols of x (hi part)
    {
      int row = t >> 4, co = (t & 15)*8;
      const unsigned short* bsrc;
      if (f32){
        int hw = hw0 + co;
        bsrc = xq + (size_t)(b*C_ + k0 + row)*8192 + (size_t)((hw >> 5)*64 + (hw & 31));
      } else {
        bsrc = (const unsigned short*)xraw + (size_t)(b*C_ + k0 + row)*HW + hw0 + co;
      }
      uint4 vv = *(const uint4*)bsrc;
      unsigned short e8[8]; *(uint4*)e8 = vv;
      #pragma unroll
      for (int kk = 0; kk < 8; ++kk) Bs[(co + kk)*LDK + row] = e8[kk];
    }
    __syncthreads();
    const int r = lane & 15, q = lane >> 4;
    bf16x8 bfr[4];
    #pragma unroll
    for (int j = 0; j < 4; ++j)
      bfr[j] = *(const bf16x8*)(Bs + (wn*64 + 16*j + r)*LDK + 8*q);
    #pragma unroll
    for (int i = 0; i < 8; ++i){
      bf16x8 af = *(const bf16x8*)(As + (size_t)(wm*128 + 16*i + r)*LDK + 8*q);
      #pragma unroll
      for (int j = 0; j < 4; ++j)
        acc[i][j] = __builtin_amdgcn_mfma_f32_16x16x32_bf16(af, bfr[j], acc[i][j], 0, 0, 0);
    }
    __syncthreads();
  }
  unsigned short* zb = z + (size_t)b*C_*HW;
  const float* b2 = bias2 + (size_t)b*C_;
  const int r = lane & 15, q = lane >> 4;
  #pragma unroll
  for (int i = 0; i < 8; ++i)
    #pragma unroll
    for (int ii = 0; ii < 4; ++ii){
      int row = wm*128 + 16*i + 4*q + ii;
      float bias = b2[row];
      #pragma unroll
      for (int j = 0; j < 4; ++j){
        int col = hw0 + wn*64 + 16*j + r;
        zb[(size_t)row*HW + col] = f2bf(acc[i][j][ii] + bias);
      }
    }
}

// ---- K7: per-channel BN stats -> scale/shift
__global__ __launch_bounds__(256) void k_bnstats(const unsigned short* __restrict__ z,
    const float* __restrict__ gamf, const float* __restrict__ betf,
    float* __restrict__ scale, float* __restrict__ shift){
  const int o = blockIdx.x, t = threadIdx.x, lane = t & 63, w = t >> 6;
  float sum = 0.f, ss = 0.f;
  for (int b = 0; b < NB; ++b){
    const unsigned short* p = z + ((size_t)b*C_ + o)*HW + t*16;
    #pragma unroll
    for (int it = 0; it < 2; ++it){
      uint4 raw = *(const uint4*)(p + it*8);
      unsigned int wd[4] = {raw.x, raw.y, raw.z, raw.w};
      #pragma unroll
      for (int k = 0; k < 4; ++k){
        float f0 = bf2f((unsigned short)(wd[k] & 0xffff));
        float f1 = bf2f((unsigned short)(wd[k] >> 16));
        sum += f0 + f1; ss += f0*f0 + f1*f1;
      }
    }
  }
  #pragma unroll
  for (int off = 1; off < 64; off <<= 1){
    sum += __shfl_xor(sum, off);
    ss  += __shfl_xor(ss, off);
  }
  __shared__ float r1[4], r2[4];
  if (lane == 0){ r1[w] = sum; r2[w] = ss; }
  __syncthreads();
  if (t == 0){
    float S1 = r1[0]+r1[1]+r1[2]+r1[3];
    float S2 = r2[0]+r2[1]+r2[2]+r2[3];
    const float n = (float)NB * (float)HW;
    float mean = S1 / n;
    float var  = S2 / n - mean*mean;
    float sc = gamf[o] * rsqrtf(var + 1e-5f);
    scale[o] = sc;
    shift[o] = betf[o] - mean*sc;
  }
}

// ---- K8: out = z*scale + shift + x
__global__ __launch_bounds__(256) void k_out(const unsigned short* __restrict__ z,
    const void* __restrict__ xraw, const int* __restrict__ flag,
    const float* __restrict__ scale, const float* __restrict__ shift, void* __restrict__ outraw){
  const bool f32 = (*flag != 0);
  const size_t g = (size_t)blockIdx.x*256 + threadIdx.x;
  const size_t base = g*8;
  const int o = (int)((base >> 12) & (C_ - 1));
  const float sc = scale[o], sh = shift[o];
  uint4 zr = *(const uint4*)(z + base);
  unsigned int zz[4] = {zr.x, zr.y, zr.z, zr.w};
  float zv[8];
  #pragma unroll
  for (int k = 0; k < 4; ++k){
    zv[2*k]   = bf2f((unsigned short)(zz[k] & 0xffff));
    zv[2*k+1] = bf2f((unsigned short)(zz[k] >> 16));
  }
  if (f32){
    const float* x = (const float*)xraw;
    float* out = (float*)outraw;
    f32x4 x0 = *(const f32x4*)(x + base);
    f32x4 x1 = *(const f32x4*)(x + base + 4);
    f32x4 o0, o1;
    #pragma unroll
    for (int k = 0; k < 4; ++k){
      o0[k] = zv[k]*sc + sh + x0[k];
      o1[k] = zv[4+k]*sc + sh + x1[k];
    }
    *(f32x4*)(out + base) = o0;
    *(f32x4*)(out + base + 4) = o1;
  } else {
    const unsigned short* x = (const unsigned short*)xraw;
    unsigned short* out = (unsigned short*)outraw;
    uint4 xr = *(const uint4*)(x + base);
    unsigned int xx[4] = {xr.x, xr.y, xr.z, xr.w};
    unsigned int res[4];
    #pragma unroll
    for (int k = 0; k < 4; ++k){
      float x0 = bf2f((unsigned short)(xx[k] & 0xffff));
      float x1 = bf2f((unsigned short)(xx[k] >> 16));
      res[k] = (unsigned int)f2bf(zv[2*k]*sc + sh + x0)
             | ((unsigned int)f2bf(zv[2*k+1]*sc + sh + x1) << 16);
    }
    uint4 ov; ov.x = res[0]; ov.y = res[1]; ov.z = res[2]; ov.w = res[3];
    *(uint4*)(out + base) = ov;
  }
}

extern "C" void kernel_launch(void* const* d_in, const int* in_sizes, int n_in,
                              void* d_out, int out_size, void* d_ws, size_t ws_size,
                              hipStream_t stream){
  (void)in_sizes; (void)n_in; (void)out_size;
  const void* x   = d_in[0];
  const void* g_w = d_in[1];
  const void* g_b = d_in[2];
  const void* t_w = d_in[3];
  const void* t_b = d_in[4];
  const void* p_w = d_in[5];
  const void* p_b = d_in[6];
  const void* W_w = d_in[7];
  const void* W_b = d_in[8];
  const void* gam = d_in[9];
  const void* bet = d_in[10];
  char* ws = (char*)d_ws;

  constexpr size_t OFF_FLAG = 0;
  constexpr size_t OFF_TWH = OFF_FLAG + 16;
  constexpr size_t OFF_TWL = OFF_TWH + (size_t)CI*C_*2;
  constexpr size_t OFF_PHH = OFF_TWL + (size_t)CI*C_*2;
  constexpr size_t OFF_PHL = OFF_PHH + (size_t)CI*C_*2;
  constexpr size_t OFF_GWC = OFF_PHL + (size_t)CI*C_*2;
  constexpr size_t OFF_WWC = OFF_GWC + (size_t)CI*C_*2;
  constexpr size_t OFF_BIA = OFF_WWC + (size_t)C_*CI*2;
  constexpr size_t OFF_GH  = OFF_BIA + 16384;
  constexpr size_t OFF_GL  = OFF_GH + (size_t)NB*C_*C_*2;
  constexpr size_t OFF_S   = OFF_GL + (size_t)NB*C_*C_*2;
  constexpr size_t OFF_U   = OFF_S  + (size_t)NB*C_*4;
  constexpr size_t OFF_V   = OFF_U  + (size_t)NB*CI*4;
  constexpr size_t OFF_TH  = OFF_V  + (size_t)NB*CI*4;
  constexpr size_t OFF_TL  = OFF_TH + (size_t)NB*CI*C_*2;
  constexpr size_t OFF_F   = OFF_TL + (size_t)NB*CI*C_*2;
  constexpr size_t OFF_SM  = OFF_F  + (size_t)NB*CI*CI*4;
  constexpr size_t OFF_M2  = OFF_SM + (size_t)NB*CI*CI*2;
  constexpr size_t OFF_B2  = OFF_M2 + (size_t)NB*C_*CI*2;
  constexpr size_t OFF_SC  = OFF_B2 + (size_t)NB*C_*4;
  constexpr size_t OFF_SH  = OFF_SC + (size_t)C_*4;
  constexpr size_t OFF_Z   = OFF_SH + (size_t)C_*4;
  constexpr size_t OFF_XQ  = OFF_Z  + (size_t)NB*C_*HW*2;
  constexpr size_t TOTAL   = OFF_XQ + (size_t)NB*C_*HW*4;   // xq: 2 bf16 per fp32 elem
  // aliases (disjoint lifetimes):
  //   Gp (fp32 Gram partials, 16*10*4*16384*4 = 41943040 B) over Z (67108864 B):
  //     Gp dead after k_gred; z written by k_zW much later.
  //   Wg (16*512*512*2 = 8388608 B) over Gh (same size): Gh's last reader k_T
  //     completes (stream order) before k_Wg writes Wg.
  static_assert((size_t)NB*10*KSPLIT*16384*4 <= (size_t)NB*C_*HW*2, "Gp alias fits in Z");
  if (ws_size < TOTAL) return;

  int* flag = (int*)(ws + OFF_FLAG);
  unsigned short* twh = (unsigned short*)(ws + OFF_TWH);
  unsigned short* twl = (unsigned short*)(ws + OFF_TWL);
  unsigned short* phh = (unsigned short*)(ws + OFF_PHH);
  unsigned short* phl = (unsigned short*)(ws + OFF_PHL);
  unsigned short* gwc = (unsigned short*)(ws + OFF_GWC);
  unsigned short* Wwc = (unsigned short*)(ws + OFF_WWC);
  float* biasf = (float*)(ws + OFF_BIA);
  unsigned short* Gh = (unsigned short*)(ws + OFF_GH);
  unsigned short* Gl = (unsigned short*)(ws + OFF_GL);
  float* s  = (float*)(ws + OFF_S);
  float* u  = (float*)(ws + OFF_U);
  float* v  = (float*)(ws + OFF_V);
  unsigned short* Th = (unsigned short*)(ws + OFF_TH);
  unsigned short* Tl = (unsigned short*)(ws + OFF_TL);
  float* f  = (float*)(ws + OFF_F);
  unsigned short* Sm = (unsigned short*)(ws + OFF_SM);
  unsigned short* M2 = (unsigned short*)(ws + OFF_M2);
  float* b2 = (float*)(ws + OFF_B2);
  unsigned short* z  = (unsigned short*)(ws + OFF_Z);
  float* scale = (float*)(ws + OFF_SC);
  float* shift = (float*)(ws + OFF_SH);
  unsigned short* xq = (unsigned short*)(ws + OFF_XQ);
  float* Gp = (float*)(ws + OFF_Z);                  // alias over Z
  unsigned short* Wg = (unsigned short*)(ws + OFF_GH); // alias over Gh (dead after k_T)

  float* gbf = biasf;          // 256
  float* tbf = biasf + 256;    // 256
  float* pbf = biasf + 512;    // 256
  float* Wbf = biasf + 768;    // 512
  float* gamf = biasf + 1280;  // 512
  float* betf = biasf + 1792;  // 512

  dim3 blk(256);
  k_detect <<<dim3(1),          blk, 0, stream>>>((const unsigned short*)x, flag);
  k_wconv  <<<dim3(2057),       blk, 0, stream>>>(t_w, p_w, g_w, W_w, g_b, t_b, p_b, W_b,
                                                  gam, bet, flag, twh, twl, phh, phl, gwc, Wwc, biasf);
  k_xconv  <<<dim3(NB*C_),      blk, 0, stream>>>(x, flag, xq, s);
  k_gram   <<<dim3(10, KSPLIT, NB), blk, 0, stream>>>(x, xq, flag, Gp);
  k_gred   <<<dim3(4, 4, NB),   blk, 0, stream>>>(Gp, Gh, Gl);
  k_T      <<<dim3(4, 2, NB),   blk, 0, stream>>>(twh, twl, flag, Gh, Gl, Th, Tl);
  k_uv     <<<dim3(NB),         blk, 0, stream>>>(twh, twl, phh, phl, s, u, v);
  k_f      <<<dim3(2, 2, NB),   blk, 0, stream>>>(Th, Tl, phh, phl, flag, f);
  k_softmax<<<dim3(64, NB),     blk, 0, stream>>>(f, u, v, tbf, pbf, Sm);
  k_M2     <<<dim3(2, 4, NB),   blk, 0, stream>>>(Wwc, Sm, M2);
  k_Wg     <<<dim3(4, 4, NB),   blk, 0, stream>>>(M2, gwc, Wg);
  k_bias2  <<<dim3(NB),         blk, 0, stream>>>(M2, gbf, Wbf, b2);
  k_zW     <<<dim3(32, 1, NB),  dim3(512), 0, stream>>>(Wg, x, xq, flag, b2, z);
  k_bnstats<<<dim3(C_),         blk, 0, stream>>>(z, gamf, betf, scale, shift);
  k_out    <<<dim3(16384),      blk, 0, stream>>>(z, x, flag, scale, shift, d_out);
}